// Round 2
// baseline (1837.784 us; speedup 1.0000x reference)
//
#include <hip/hip_runtime.h>
#include <hip/hip_bf16.h>
#include <math.h>

#define HDIM   768
#define INNER  1152
#define NHEADS 8
#define DHEAD  144
#define SEQ    2048
#define BATCH  2
#define TOKENS (BATCH*SEQ)

using bf16x8 = __attribute__((ext_vector_type(8))) short;
using u16x8  = __attribute__((ext_vector_type(8))) unsigned short;
using f32x4  = __attribute__((ext_vector_type(4))) float;

__device__ __forceinline__ float silu_f(float x) { return x / (1.f + expf(-x)); }

__device__ __forceinline__ unsigned short f2bf(float f) {
    unsigned u = __float_as_uint(f);
    unsigned r = (u + 0x7fffu + ((u >> 16) & 1u)) >> 16;
    return (unsigned short)r;
}
__device__ __forceinline__ float bf2f(unsigned short s) {
    return __uint_as_float(((unsigned)s) << 16);
}

// ---------------------------------------------------------------------------
// convert fp32 activation [M][ldx] (first Kd cols) -> hi/lo bf16 tiles
// layout: [rb][kb][2][128][32], rb=row/128, kb=k/32
// ---------------------------------------------------------------------------
__global__ __launch_bounds__(256) void convert_act(
    const float* __restrict__ X, int ldx, int Kd, unsigned short* __restrict__ Y) {
    int t = blockIdx.x * 256 + threadIdx.x;       // M*(Kd/8) threads
    int kc = Kd >> 3;
    int k8 = t % kc;
    int row = t / kc;
    int k = k8 * 8;
    const float* src = X + (size_t)row * ldx + k;
    float4 v0 = *(const float4*)src;
    float4 v1 = *(const float4*)(src + 4);
    float a[8] = {v0.x, v0.y, v0.z, v0.w, v1.x, v1.y, v1.z, v1.w};
    u16x8 hi, lo;
#pragma unroll
    for (int j = 0; j < 8; ++j) {
        unsigned short h = f2bf(a[j]);
        hi[j] = h;
        lo[j] = f2bf(a[j] - bf2f(h));
    }
    int rb = row >> 7, r = row & 127, kb = k >> 5, c = k & 31;
    int KB = Kd >> 5;
    size_t base = ((size_t)(rb * KB + kb) * 2) * 4096;
    *(u16x8*)&Y[base + r * 32 + c] = hi;
    *(u16x8*)&Y[base + 4096 + r * 32 + c] = lo;
}

// ---------------------------------------------------------------------------
// convert fp32 weight [Kd][N] -> TRANSPOSED hi/lo bf16 tiles
// layout: [cb][kb][2][128 cols][32 k]
// ---------------------------------------------------------------------------
__global__ __launch_bounds__(256) void convert_wgt(
    const float* __restrict__ W, int N, int Kd, unsigned short* __restrict__ Y) {
    __shared__ float ls[32][133];
    const int tid = threadIdx.x;
    const int cb = blockIdx.x, kb = blockIdx.y;
    for (int i = tid; i < 4096; i += 256) {
        int kk = i >> 7, n = i & 127;
        ls[kk][n] = W[(size_t)(kb * 32 + kk) * N + cb * 128 + n];
    }
    __syncthreads();
    int KB = Kd >> 5;
    unsigned short* dst = Y + ((size_t)(cb * KB + kb) * 2) * 4096;
#pragma unroll
    for (int g = 0; g < 2; ++g) {
        int u = g * 256 + tid;          // 0..511
        int j = u >> 2, kk0 = (u & 3) * 8;
        u16x8 hi, lo;
#pragma unroll
        for (int e = 0; e < 8; ++e) {
            float a = ls[kk0 + e][j];
            unsigned short h = f2bf(a);
            hi[e] = h;
            lo[e] = f2bf(a - bf2f(h));
        }
        *(u16x8*)&dst[j * 32 + kk0] = hi;
        *(u16x8*)&dst[4096 + j * 32 + kk0] = lo;
    }
}

// ---------------------------------------------------------------------------
// bf16x3 MFMA GEMM: C[M,N](fp32) = A[M,K] @ B[K,N] where operands are hi/lo
// tiled bf16 (A: [rb][kb][2][128][32], B transposed: [cb][kb][2][128][32]).
// 128x128 tile, BK=32, 256 threads (4 waves, 2x2), 4x4 16x16x32 frags/wave,
// 3 MFMA per fragment pair (Ah*Bh + Ah*Bl + Al*Bh). m97-style 2-barrier loop.
// ---------------------------------------------------------------------------
__global__ __launch_bounds__(256) void gemm_bf16x3(
    const unsigned short* __restrict__ At, const unsigned short* __restrict__ Bt,
    float* __restrict__ C, int N, int KB) {
    __shared__ unsigned short lsA[2][128][32];
    __shared__ unsigned short lsB[2][128][32];
    const int tid = threadIdx.x;
    const int w = tid >> 6, lane = tid & 63;
    const int wr = w >> 1, wc = w & 1;
    const int bx = blockIdx.x, by = blockIdx.y;

    const unsigned short* ga0 = At + ((size_t)by * KB) * 8192;
    const unsigned short* gb0 = Bt + ((size_t)bx * KB) * 8192;
    unsigned short* lsAf = &lsA[0][0][0];
    unsigned short* lsBf = &lsB[0][0][0];

    f32x4 acc[4][4];
#pragma unroll
    for (int i = 0; i < 4; ++i)
#pragma unroll
        for (int j = 0; j < 4; ++j) acc[i][j] = (f32x4){0.f, 0.f, 0.f, 0.f};

    const int kseg = (lane >> 4) * 8;
    const int rl = lane & 15;

    for (int kb = 0; kb < KB; ++kb) {
        __syncthreads();                     // previous iter's reads done
        const unsigned short* ga = ga0 + (size_t)kb * 8192;
        const unsigned short* gb = gb0 + (size_t)kb * 8192;
#pragma unroll
        for (int p = 0; p < 4; ++p) {
            int chunk = p * 4 + w;           // 16 chunks x 1KB cover 16KB tilepair
            __builtin_amdgcn_global_load_lds(
                (const __attribute__((address_space(1))) void*)(ga + chunk * 512 + lane * 8),
                (__attribute__((address_space(3))) void*)(lsAf + chunk * 512), 16, 0, 0);
            __builtin_amdgcn_global_load_lds(
                (const __attribute__((address_space(1))) void*)(gb + chunk * 512 + lane * 8),
                (__attribute__((address_space(3))) void*)(lsBf + chunk * 512), 16, 0, 0);
        }
        __syncthreads();                     // drains vmcnt -> LDS ready

        bf16x8 ah[4], al[4], bh[4], bl[4];
#pragma unroll
        for (int f = 0; f < 4; ++f) {
            ah[f] = *(const bf16x8*)&lsA[0][wr * 64 + f * 16 + rl][kseg];
            al[f] = *(const bf16x8*)&lsA[1][wr * 64 + f * 16 + rl][kseg];
            bh[f] = *(const bf16x8*)&lsB[0][wc * 64 + f * 16 + rl][kseg];
            bl[f] = *(const bf16x8*)&lsB[1][wc * 64 + f * 16 + rl][kseg];
        }
#pragma unroll
        for (int i = 0; i < 4; ++i)
#pragma unroll
            for (int j = 0; j < 4; ++j) {
                acc[i][j] = __builtin_amdgcn_mfma_f32_16x16x32_bf16(ah[i], bh[j], acc[i][j], 0, 0, 0);
                acc[i][j] = __builtin_amdgcn_mfma_f32_16x16x32_bf16(ah[i], bl[j], acc[i][j], 0, 0, 0);
                acc[i][j] = __builtin_amdgcn_mfma_f32_16x16x32_bf16(al[i], bh[j], acc[i][j], 0, 0, 0);
            }
    }

    const int cl = lane & 15, rseg = (lane >> 4) * 4;
#pragma unroll
    for (int i = 0; i < 4; ++i)
#pragma unroll
        for (int j = 0; j < 4; ++j)
#pragma unroll
            for (int r = 0; r < 4; ++r)
                C[(size_t)(by * 128 + wr * 64 + i * 16 + rseg + r) * N +
                  bx * 128 + wc * 64 + j * 16 + cl] = acc[i][j][r];
}

// ---------------------------------------------------------------------------
// causal depthwise conv1d (K=4) + bias + silu; writes fp32 xconv AND hi/lo
// tiled bf16 (GEMM-A layout) in one pass. 8 channels per thread.
// ---------------------------------------------------------------------------
__global__ __launch_bounds__(256) void conv_silu_cvt(
    const float* __restrict__ xz, const float* __restrict__ cw,
    const float* __restrict__ cb, float* __restrict__ xconv,
    unsigned short* __restrict__ ct) {
    int t = blockIdx.x * 256 + threadIdx.x;      // TOKENS*144
    int c8 = t % 144;
    int row = t / 144;
    int c = c8 * 8;
    int s = row & (SEQ - 1);
    float acc[8];
#pragma unroll
    for (int j = 0; j < 8; ++j) acc[j] = cb[c + j];
#pragma unroll
    for (int tap = 0; tap < 4; ++tap) {
        int ss = s - 3 + tap;
        if (ss < 0) continue;
        const float* src = xz + (size_t)(row - 3 + tap) * (2 * INNER) + c;
        float4 v0 = *(const float4*)src;
        float4 v1 = *(const float4*)(src + 4);
        float vv[8] = {v0.x, v0.y, v0.z, v0.w, v1.x, v1.y, v1.z, v1.w};
#pragma unroll
        for (int j = 0; j < 8; ++j) acc[j] += vv[j] * cw[(c + j) * 4 + tap];
    }
    float xc[8];
    u16x8 hi, lo;
#pragma unroll
    for (int j = 0; j < 8; ++j) {
        xc[j] = silu_f(acc[j]);
        unsigned short h = f2bf(xc[j]);
        hi[j] = h;
        lo[j] = f2bf(xc[j] - bf2f(h));
    }
    float4 o0 = {xc[0], xc[1], xc[2], xc[3]};
    float4 o1 = {xc[4], xc[5], xc[6], xc[7]};
    *(float4*)&xconv[(size_t)row * INNER + c] = o0;
    *(float4*)&xconv[(size_t)row * INNER + c + 4] = o1;
    int rb = row >> 7, r = row & 127, kb = c >> 5, cc = c & 31;
    size_t base = ((size_t)(rb * 36 + kb) * 2) * 4096;
    *(u16x8*)&ct[base + r * 32 + cc] = hi;
    *(u16x8*)&ct[base + 4096 + r * 32 + cc] = lo;
}

// ---------------------------------------------------------------------------
// gates: ig/fg = [q,k,v] @ Wi/Wf + bi/bf per token
// ---------------------------------------------------------------------------
__global__ __launch_bounds__(256) void gates_kernel(
    const float* __restrict__ qb, const float* __restrict__ kb,
    const float* __restrict__ vb, const float* __restrict__ Wi,
    const float* __restrict__ bi, const float* __restrict__ Wf,
    const float* __restrict__ bf, float* __restrict__ ig, float* __restrict__ logf) {
    __shared__ float red[16][257];
    const int tok = blockIdx.x;
    const int tid = threadIdx.x;
    float aI[8], aF[8];
#pragma unroll
    for (int h = 0; h < 8; ++h) { aI[h] = 0.f; aF[h] = 0.f; }
    const size_t rb = (size_t)tok * INNER;
    for (int d = tid; d < INNER; d += 256) {
        float qv = qb[rb + d], kv = kb[rb + d], vv = vb[rb + d];
        float4 wq0 = *(const float4*)&Wi[(size_t)d * 8];
        float4 wq1 = *(const float4*)&Wi[(size_t)d * 8 + 4];
        float4 wk0 = *(const float4*)&Wi[(size_t)(INNER + d) * 8];
        float4 wk1 = *(const float4*)&Wi[(size_t)(INNER + d) * 8 + 4];
        float4 wv0 = *(const float4*)&Wi[(size_t)(2 * INNER + d) * 8];
        float4 wv1 = *(const float4*)&Wi[(size_t)(2 * INNER + d) * 8 + 4];
        aI[0] += qv * wq0.x + kv * wk0.x + vv * wv0.x;
        aI[1] += qv * wq0.y + kv * wk0.y + vv * wv0.y;
        aI[2] += qv * wq0.z + kv * wk0.z + vv * wv0.z;
        aI[3] += qv * wq0.w + kv * wk0.w + vv * wv0.w;
        aI[4] += qv * wq1.x + kv * wk1.x + vv * wv1.x;
        aI[5] += qv * wq1.y + kv * wk1.y + vv * wv1.y;
        aI[6] += qv * wq1.z + kv * wk1.z + vv * wv1.z;
        aI[7] += qv * wq1.w + kv * wk1.w + vv * wv1.w;
        float4 fq0 = *(const float4*)&Wf[(size_t)d * 8];
        float4 fq1 = *(const float4*)&Wf[(size_t)d * 8 + 4];
        float4 fk0 = *(const float4*)&Wf[(size_t)(INNER + d) * 8];
        float4 fk1 = *(const float4*)&Wf[(size_t)(INNER + d) * 8 + 4];
        float4 fv0 = *(const float4*)&Wf[(size_t)(2 * INNER + d) * 8];
        float4 fv1 = *(const float4*)&Wf[(size_t)(2 * INNER + d) * 8 + 4];
        aF[0] += qv * fq0.x + kv * fk0.x + vv * fv0.x;
        aF[1] += qv * fq0.y + kv * fk0.y + vv * fv0.y;
        aF[2] += qv * fq0.z + kv * fk0.z + vv * fv0.z;
        aF[3] += qv * fq0.w + kv * fk0.w + vv * fv0.w;
        aF[4] += qv * fq1.x + kv * fk1.x + vv * fv1.x;
        aF[5] += qv * fq1.y + kv * fk1.y + vv * fv1.y;
        aF[6] += qv * fq1.z + kv * fk1.z + vv * fv1.z;
        aF[7] += qv * fq1.w + kv * fk1.w + vv * fv1.w;
    }
#pragma unroll
    for (int h = 0; h < 8; ++h) { red[h][tid] = aI[h]; red[8 + h][tid] = aF[h]; }
    __syncthreads();
    for (int off = 128; off > 0; off >>= 1) {
        if (tid < off) {
#pragma unroll
            for (int h = 0; h < 16; ++h) red[h][tid] += red[h][tid + off];
        }
        __syncthreads();
    }
    if (tid < 8) {
        int h = tid;
        int b = tok / SEQ, s = tok % SEQ;
        size_t gidx = (size_t)(b * NHEADS + h) * SEQ + s;
        ig[gidx] = red[h][0] + bi[h];
        float fgv = red[8 + h][0] + bf[h];
        float lf = fminf(fgv, 0.f) - log1pf(expf(-fabsf(fgv)));
        logf[gidx] = lf;
    }
}

// ---------------------------------------------------------------------------
__global__ __launch_bounds__(256) void cumsum_seq(float* __restrict__ buf) {
    __shared__ float ts[256];
    const int tid = threadIdx.x;
    const size_t base = (size_t)blockIdx.x * SEQ;
    float v[8];
    float run = 0.f;
#pragma unroll
    for (int j = 0; j < 8; ++j) { run += buf[base + tid * 8 + j]; v[j] = run; }
    ts[tid] = run;
    __syncthreads();
    for (int off = 1; off < 256; off <<= 1) {
        float add = (tid >= off) ? ts[tid - off] : 0.f;
        __syncthreads();
        ts[tid] += add;
        __syncthreads();
    }
    float excl = (tid > 0) ? ts[tid - 1] : 0.f;
#pragma unroll
    for (int j = 0; j < 8; ++j) buf[base + tid * 8 + j] = v[j] + excl;
}

// ---------------------------------------------------------------------------
// flash-style mLSTM cell (fp32).
// ---------------------------------------------------------------------------
#define QT 32
#define KT 32
#define RS 148

__global__ __launch_bounds__(256) void mlstm_cell(
    const float* __restrict__ qb, const float* __restrict__ kb,
    const float* __restrict__ vb, const float* __restrict__ ig,
    const float* __restrict__ cs, float* __restrict__ hcell) {
    __shared__ float Qs[QT][RS];
    __shared__ float Ks[KT][RS];
    __shared__ float Vs[KT][RS];
    __shared__ float P[QT][KT + 1];
    __shared__ float ej[KT];
    __shared__ float csq[QT], mrow[QT], ssum[QT], scl[QT], arow[QT];

    const int tid = threadIdx.x;
    const int bh = blockIdx.x;
    const int b = bh / NHEADS, h = bh % NHEADS;
    const int qt = blockIdx.y;
    const int qi0 = qt * QT;
    const size_t qrow0 = ((size_t)(b * SEQ + qi0)) * INNER + h * DHEAD;
    const int gbase = bh * SEQ;

    for (int idx = tid; idx < QT * (DHEAD / 4); idx += 256) {
        int r = idx / (DHEAD / 4), d4 = (idx % (DHEAD / 4)) * 4;
        *(float4*)&Qs[r][d4] = *(const float4*)&qb[qrow0 + (size_t)r * INNER + d4];
    }
    if (tid < QT) {
        csq[tid] = cs[gbase + qi0 + tid];
        mrow[tid] = -INFINITY;
        ssum[tid] = 0.f;
    }
    float o[18];
#pragma unroll
    for (int j = 0; j < 18; ++j) o[j] = 0.f;

    const int pr = tid >> 3;
    const int pd = (tid & 7) * 18;
    const int r0 = (tid >> 4) << 1;
    const int c0 = (tid & 15) << 1;

    for (int kt = 0; kt <= qt; ++kt) {
        __syncthreads();
        const int kj0 = kt * KT;
        const size_t krow0 = ((size_t)(b * SEQ + kj0)) * INNER + h * DHEAD;
        for (int idx = tid; idx < KT * (DHEAD / 4); idx += 256) {
            int r = idx / (DHEAD / 4), d4 = (idx % (DHEAD / 4)) * 4;
            *(float4*)&Ks[r][d4] = *(const float4*)&kb[krow0 + (size_t)r * INNER + d4];
            *(float4*)&Vs[r][d4] = *(const float4*)&vb[krow0 + (size_t)r * INNER + d4];
        }
        if (tid < KT) ej[tid] = ig[gbase + kj0 + tid] - cs[gbase + kj0 + tid];
        __syncthreads();

        float s00 = 0, s01 = 0, s10 = 0, s11 = 0;
#pragma unroll 4
        for (int d = 0; d < DHEAD; d += 4) {
            float4 qa = *(float4*)&Qs[r0][d];
            float4 qc = *(float4*)&Qs[r0 + 1][d];
            float4 ka = *(float4*)&Ks[c0][d];
            float4 kc = *(float4*)&Ks[c0 + 1][d];
            s00 += qa.x * ka.x + qa.y * ka.y + qa.z * ka.z + qa.w * ka.w;
            s01 += qa.x * kc.x + qa.y * kc.y + qa.z * kc.z + qa.w * kc.w;
            s10 += qc.x * ka.x + qc.y * ka.y + qc.z * ka.z + qc.w * ka.w;
            s11 += qc.x * kc.x + qc.y * kc.y + qc.z * kc.z + qc.w * kc.w;
        }
        const float qsc = 1.f / 12.f;
        P[r0][c0] = s00 * qsc;
        P[r0][c0 + 1] = s01 * qsc;
        P[r0 + 1][c0] = s10 * qsc;
        P[r0 + 1][c0 + 1] = s11 * qsc;
        __syncthreads();

        if (tid < QT) {
            int r = tid;
            float e = ej[0];
            int lim = (kt == qt) ? r : (KT - 1);
            for (int c = 1; c <= lim; ++c) e = fmaxf(e, ej[c]);
            float mt = csq[r] + e;
            float mo = mrow[r];
            float mn = fmaxf(mo, mt);
            scl[r] = expf(mo - mn);
            arow[r] = csq[r] - mn;
            mrow[r] = mn;
        }
        __syncthreads();

#pragma unroll
        for (int i = 0; i < 2; ++i) {
            int rr = r0 + i;
            float ar = arow[rr];
#pragma unroll
            for (int j = 0; j < 2; ++j) {
                int cc = c0 + j;
                float pv;
                if (kt == qt && cc > rr) pv = 0.f;
                else pv = P[rr][cc] * expf(ar + ej[cc]);
                P[rr][cc] = pv;
            }
        }
        __syncthreads();

        if (tid < QT) {
            float rs = 0.f;
            for (int c = 0; c < KT; ++c) rs += P[tid][c];
            ssum[tid] = ssum[tid] * scl[tid] + rs;
        }

        float sc = scl[pr];
#pragma unroll
        for (int j = 0; j < 18; ++j) o[j] *= sc;
        for (int c = 0; c < KT; ++c) {
            float p = P[pr][c];
#pragma unroll
            for (int j = 0; j < 18; ++j) o[j] += p * Vs[c][pd + j];
        }
    }
    __syncthreads();
    float nrm = fmaxf(fabsf(ssum[pr]), expf(-mrow[pr])) + 1e-6f;
    float inv = 1.f / nrm;
#pragma unroll
    for (int j = 0; j < 18; ++j)
        hcell[qrow0 + (size_t)pr * INNER + pd + j] = o[j] * inv;
}

// ---------------------------------------------------------------------------
// per-head layernorm * norm_w + skip*x_conv, then * silu(z)
// ---------------------------------------------------------------------------
__global__ __launch_bounds__(256) void ln_gate(
    const float* __restrict__ hcell, const float* __restrict__ xconv,
    const float* __restrict__ xz, const float* __restrict__ norm_w,
    const float* __restrict__ skip, float* __restrict__ g) {
    const int unit = blockIdx.x * 4 + (threadIdx.x >> 6);
    const int lane = threadIdx.x & 63;
    const int token = unit >> 3;
    const int h = unit & 7;
    const size_t base = (size_t)token * INNER + h * DHEAD;

    float x0 = hcell[base + lane];
    float x1 = hcell[base + 64 + lane];
    float x2 = (lane < 16) ? hcell[base + 128 + lane] : 0.f;
    float s = x0 + x1 + x2;
#pragma unroll
    for (int off = 32; off > 0; off >>= 1) s += __shfl_down(s, off);
    s = __shfl(s, 0);
    float mean = s * (1.f / 144.f);
    float d0 = x0 - mean, d1 = x1 - mean, d2 = (lane < 16) ? x2 - mean : 0.f;
    float vsum = d0 * d0 + d1 * d1 + d2 * d2;
#pragma unroll
    for (int off = 32; off > 0; off >>= 1) vsum += __shfl_down(vsum, off);
    vsum = __shfl(vsum, 0);
    float rstd = rsqrtf(vsum * (1.f / 144.f) + 1e-5f);
    float sk = skip[0];
    const size_t zbase = (size_t)token * (2 * INNER) + INNER + h * DHEAD;

    {
        float hn = d0 * rstd * norm_w[h * DHEAD + lane];
        g[base + lane] = (hn + sk * xconv[base + lane]) * silu_f(xz[zbase + lane]);
    }
    {
        float hn = d1 * rstd * norm_w[h * DHEAD + 64 + lane];
        g[base + 64 + lane] = (hn + sk * xconv[base + 64 + lane]) * silu_f(xz[zbase + 64 + lane]);
    }
    if (lane < 16) {
        float hn = d2 * rstd * norm_w[h * DHEAD + 128 + lane];
        g[base + 128 + lane] = (hn + sk * xconv[base + 128 + lane]) * silu_f(xz[zbase + 128 + lane]);
    }
}

// ---------------------------------------------------------------------------
extern "C" void kernel_launch(void* const* d_in, const int* in_sizes, int n_in,
                              void* d_out, int out_size, void* d_ws, size_t ws_size,
                              hipStream_t stream) {
    const float* x      = (const float*)d_in[0];
    const float* W_up   = (const float*)d_in[1];
    const float* conv_w = (const float*)d_in[2];
    const float* conv_b = (const float*)d_in[3];
    const float* Wq     = (const float*)d_in[4];
    const float* Wk     = (const float*)d_in[5];
    const float* Wv     = (const float*)d_in[6];
    const float* Wi     = (const float*)d_in[7];
    const float* bi     = (const float*)d_in[8];
    const float* Wf     = (const float*)d_in[9];
    const float* bf     = (const float*)d_in[10];
    const float* norm_w = (const float*)d_in[11];
    const float* skip   = (const float*)d_in[12];
    const float* W_down = (const float*)d_in[13];
    float* out = (float*)d_out;

    float* f = (float*)d_ws;
    float* xz    = f; f += 9437184;          // TOKENS*2*INNER
    float* xconv = f; f += 4718592;          // TOKENS*INNER
    float* qb    = f; f += 4718592;
    float* kbuf  = f; f += 4718592;
    float* vb    = f; f += 4718592;
    float* hcell = f; f += 4718592;
    float* igb   = f; f += 32768;
    float* csb   = f; f += 32768;
    unsigned short* xh  = (unsigned short*)f; f += 3145728;  // 4096*768*2 bf16
    unsigned short* ch  = (unsigned short*)f; f += 4718592;  // 4096*1152*2 bf16
    unsigned short* mh  = (unsigned short*)f; f += 4718592;
    unsigned short* gh  = (unsigned short*)f; f += 4718592;
    unsigned short* wup = (unsigned short*)f; f += 1769472;  // 768*2304*2 bf16
    unsigned short* wqt = (unsigned short*)f; f += 1327104;  // 1152*1152*2
    unsigned short* wkt = (unsigned short*)f; f += 1327104;
    unsigned short* wvt = (unsigned short*)f; f += 1327104;
    unsigned short* wdt = (unsigned short*)f; f += 884736;   // 1152*768*2

    dim3 blk(256);

    // weight conversions (transpose + hi/lo split + tiling)
    convert_wgt<<<dim3(18, 24), blk, 0, stream>>>(W_up, 2304, 768, wup);
    convert_wgt<<<dim3(9, 36), blk, 0, stream>>>(Wq, 1152, 1152, wqt);
    convert_wgt<<<dim3(9, 36), blk, 0, stream>>>(Wk, 1152, 1152, wkt);
    convert_wgt<<<dim3(9, 36), blk, 0, stream>>>(Wv, 1152, 1152, wvt);
    convert_wgt<<<dim3(6, 36), blk, 0, stream>>>(W_down, 768, 1152, wdt);

    // x -> hi/lo tiles; xz = x @ W_up
    convert_act<<<1536, blk, 0, stream>>>(x, HDIM, HDIM, xh);
    gemm_bf16x3<<<dim3(18, 32), blk, 0, stream>>>(xh, wup, xz, 2304, 24);

    // conv + silu (+ tiles); x_mlstm -> tiles
    conv_silu_cvt<<<2304, blk, 0, stream>>>(xz, conv_w, conv_b, xconv, ch);
    convert_act<<<2304, blk, 0, stream>>>(xz, 2 * INNER, INNER, mh);

    // q, k, v
    gemm_bf16x3<<<dim3(9, 32), blk, 0, stream>>>(ch, wqt, qb, INNER, 36);
    gemm_bf16x3<<<dim3(9, 32), blk, 0, stream>>>(ch, wkt, kbuf, INNER, 36);
    gemm_bf16x3<<<dim3(9, 32), blk, 0, stream>>>(mh, wvt, vb, INNER, 36);

    // gates + cumsum + cell
    gates_kernel<<<TOKENS, blk, 0, stream>>>(qb, kbuf, vb, Wi, bi, Wf, bf, igb, csb);
    cumsum_seq<<<BATCH * NHEADS, blk, 0, stream>>>(csb);
    mlstm_cell<<<dim3(BATCH * NHEADS, SEQ / QT), blk, 0, stream>>>(qb, kbuf, vb, igb, csb, hcell);

    // LN + skip + z-gate (into qb), convert, down-proj
    ln_gate<<<TOKENS * NHEADS / 4, blk, 0, stream>>>(hcell, xconv, xz, norm_w, skip, qb);
    convert_act<<<2304, blk, 0, stream>>>(qb, INNER, INNER, gh);
    gemm_bf16x3<<<dim3(6, 32), blk, 0, stream>>>(gh, wdt, out, HDIM, 36);
}

// Round 11
// 825.915 us; speedup vs baseline: 2.2251x; 2.2251x over previous
//
#include <hip/hip_runtime.h>
#include <hip/hip_bf16.h>
#include <math.h>

#define HDIM   768
#define INNER  1152
#define NHEADS 8
#define DHEAD  144
#define SEQ    2048
#define BATCH  2
#define TOKENS (BATCH*SEQ)

using bf16x8 = __attribute__((ext_vector_type(8))) short;
using u16x8  = __attribute__((ext_vector_type(8))) unsigned short;
using f32x4  = __attribute__((ext_vector_type(4))) float;

__device__ __forceinline__ float silu_f(float x) { return x / (1.f + expf(-x)); }

__device__ __forceinline__ unsigned short f2bf(float f) {
    unsigned u = __float_as_uint(f);
    unsigned r = (u + 0x7fffu + ((u >> 16) & 1u)) >> 16;
    return (unsigned short)r;
}
__device__ __forceinline__ float bf2f(unsigned short s) {
    return __uint_as_float(((unsigned)s) << 16);
}

#define MF(a, b, c) __builtin_amdgcn_mfma_f32_16x16x32_bf16(a, b, c, 0, 0, 0)

// ---------------------------------------------------------------------------
// convert fp32 activation [M][ldx] (first Kd cols) -> hi/lo bf16 tiles
// layout: [rb][kb][2][128][32], rb=row/128, kb=k/32   (GEMM A-operand)
// ---------------------------------------------------------------------------
__global__ __launch_bounds__(256) void convert_act(
    const float* __restrict__ X, int ldx, int Kd, unsigned short* __restrict__ Y) {
    int t = blockIdx.x * 256 + threadIdx.x;
    int kc = Kd >> 3;
    int k8 = t % kc;
    int row = t / kc;
    int k = k8 * 8;
    const float* src = X + (size_t)row * ldx + k;
    float4 v0 = *(const float4*)src;
    float4 v1 = *(const float4*)(src + 4);
    float a[8] = {v0.x, v0.y, v0.z, v0.w, v1.x, v1.y, v1.z, v1.w};
    u16x8 hi, lo;
#pragma unroll
    for (int j = 0; j < 8; ++j) {
        unsigned short h = f2bf(a[j]);
        hi[j] = h;
        lo[j] = f2bf(a[j] - bf2f(h));
    }
    int rb = row >> 7, r = row & 127, kb = k >> 5, c = k & 31;
    int KB = Kd >> 5;
    size_t base = ((size_t)(rb * KB + kb) * 2) * 4096;
    *(u16x8*)&Y[base + r * 32 + c] = hi;
    *(u16x8*)&Y[base + 4096 + r * 32 + c] = lo;
}

// ---------------------------------------------------------------------------
// convert fp32 weight [Kd][N] -> TRANSPOSED hi/lo bf16 tiles [cb][kb][2][128][32]
// ---------------------------------------------------------------------------
__global__ __launch_bounds__(256) void convert_wgt(
    const float* __restrict__ W, int N, int Kd, unsigned short* __restrict__ Y) {
    __shared__ float ls[32][133];
    const int tid = threadIdx.x;
    const int cb = blockIdx.x, kb = blockIdx.y;
    for (int i = tid; i < 4096; i += 256) {
        int kk = i >> 7, n = i & 127;
        ls[kk][n] = W[(size_t)(kb * 32 + kk) * N + cb * 128 + n];
    }
    __syncthreads();
    int KB = Kd >> 5;
    unsigned short* dst = Y + ((size_t)(cb * KB + kb) * 2) * 4096;
#pragma unroll
    for (int g = 0; g < 2; ++g) {
        int u = g * 256 + tid;
        int j = u >> 2, kk0 = (u & 3) * 8;
        u16x8 hi, lo;
#pragma unroll
        for (int e = 0; e < 8; ++e) {
            float a = ls[kk0 + e][j];
            unsigned short h = f2bf(a);
            hi[e] = h;
            lo[e] = f2bf(a - bf2f(h));
        }
        *(u16x8*)&dst[j * 32 + kk0] = hi;
        *(u16x8*)&dst[4096 + j * 32 + kk0] = lo;
    }
}

// ---------------------------------------------------------------------------
// bf16x3 MFMA GEMM (m97-style 2-barrier loop, global_load_lds w=16)
// ---------------------------------------------------------------------------
__global__ __launch_bounds__(256) void gemm_bf16x3(
    const unsigned short* __restrict__ At, const unsigned short* __restrict__ Bt,
    float* __restrict__ C, int N, int KB) {
    __shared__ unsigned short lsA[2][128][32];
    __shared__ unsigned short lsB[2][128][32];
    const int tid = threadIdx.x;
    const int w = tid >> 6, lane = tid & 63;
    const int wr = w >> 1, wc = w & 1;
    const int bx = blockIdx.x, by = blockIdx.y;

    const unsigned short* ga0 = At + ((size_t)by * KB) * 8192;
    const unsigned short* gb0 = Bt + ((size_t)bx * KB) * 8192;
    unsigned short* lsAf = &lsA[0][0][0];
    unsigned short* lsBf = &lsB[0][0][0];

    f32x4 acc[4][4];
#pragma unroll
    for (int i = 0; i < 4; ++i)
#pragma unroll
        for (int j = 0; j < 4; ++j) acc[i][j] = (f32x4){0.f, 0.f, 0.f, 0.f};

    const int kseg = (lane >> 4) * 8;
    const int rl = lane & 15;

    for (int kb = 0; kb < KB; ++kb) {
        __syncthreads();
        const unsigned short* ga = ga0 + (size_t)kb * 8192;
        const unsigned short* gb = gb0 + (size_t)kb * 8192;
#pragma unroll
        for (int p = 0; p < 4; ++p) {
            int chunk = p * 4 + w;
            __builtin_amdgcn_global_load_lds(
                (const __attribute__((address_space(1))) void*)(ga + chunk * 512 + lane * 8),
                (__attribute__((address_space(3))) void*)(lsAf + chunk * 512), 16, 0, 0);
            __builtin_amdgcn_global_load_lds(
                (const __attribute__((address_space(1))) void*)(gb + chunk * 512 + lane * 8),
                (__attribute__((address_space(3))) void*)(lsBf + chunk * 512), 16, 0, 0);
        }
        __syncthreads();

        bf16x8 ah[4], al[4], bh[4], bl[4];
#pragma unroll
        for (int f = 0; f < 4; ++f) {
            ah[f] = *(const bf16x8*)&lsA[0][wr * 64 + f * 16 + rl][kseg];
            al[f] = *(const bf16x8*)&lsA[1][wr * 64 + f * 16 + rl][kseg];
            bh[f] = *(const bf16x8*)&lsB[0][wc * 64 + f * 16 + rl][kseg];
            bl[f] = *(const bf16x8*)&lsB[1][wc * 64 + f * 16 + rl][kseg];
        }
#pragma unroll
        for (int i = 0; i < 4; ++i)
#pragma unroll
            for (int j = 0; j < 4; ++j) {
                acc[i][j] = MF(ah[i], bh[j], acc[i][j]);
                acc[i][j] = MF(ah[i], bl[j], acc[i][j]);
                acc[i][j] = MF(al[i], bh[j], acc[i][j]);
            }
    }

    const int cl = lane & 15, rseg = (lane >> 4) * 4;
#pragma unroll
    for (int i = 0; i < 4; ++i)
#pragma unroll
        for (int j = 0; j < 4; ++j)
#pragma unroll
            for (int r = 0; r < 4; ++r)
                C[(size_t)(by * 128 + wr * 64 + i * 16 + rseg + r) * N +
                  bx * 128 + wc * 64 + j * 16 + cl] = acc[i][j][r];
}

// ---------------------------------------------------------------------------
// causal depthwise conv1d (K=4) + bias + silu; fp32 out + GEMM-A bf16 tiles
// ---------------------------------------------------------------------------
__global__ __launch_bounds__(256) void conv_silu_cvt(
    const float* __restrict__ xz, const float* __restrict__ cw,
    const float* __restrict__ cb, float* __restrict__ xconv,
    unsigned short* __restrict__ ct) {
    int t = blockIdx.x * 256 + threadIdx.x;
    int c8 = t % 144;
    int row = t / 144;
    int c = c8 * 8;
    int s = row & (SEQ - 1);
    float acc[8];
#pragma unroll
    for (int j = 0; j < 8; ++j) acc[j] = cb[c + j];
#pragma unroll
    for (int tap = 0; tap < 4; ++tap) {
        int ss = s - 3 + tap;
        if (ss < 0) continue;
        const float* src = xz + (size_t)(row - 3 + tap) * (2 * INNER) + c;
        float4 v0 = *(const float4*)src;
        float4 v1 = *(const float4*)(src + 4);
        float vv[8] = {v0.x, v0.y, v0.z, v0.w, v1.x, v1.y, v1.z, v1.w};
#pragma unroll
        for (int j = 0; j < 8; ++j) acc[j] += vv[j] * cw[(c + j) * 4 + tap];
    }
    float xc[8];
    u16x8 hi, lo;
#pragma unroll
    for (int j = 0; j < 8; ++j) {
        xc[j] = silu_f(acc[j]);
        unsigned short h = f2bf(xc[j]);
        hi[j] = h;
        lo[j] = f2bf(xc[j] - bf2f(h));
    }
    float4 o0 = {xc[0], xc[1], xc[2], xc[3]};
    float4 o1 = {xc[4], xc[5], xc[6], xc[7]};
    *(float4*)&xconv[(size_t)row * INNER + c] = o0;
    *(float4*)&xconv[(size_t)row * INNER + c + 4] = o1;
    int rb = row >> 7, r = row & 127, kb = c >> 5, cc = c & 31;
    size_t base = ((size_t)(rb * 36 + kb) * 2) * 4096;
    *(u16x8*)&ct[base + r * 32 + cc] = hi;
    *(u16x8*)&ct[base + 4096 + r * 32 + cc] = lo;
}

// ---------------------------------------------------------------------------
// gates: ig/fg = [q,k,v] @ Wi/Wf + bi/bf per token
// ---------------------------------------------------------------------------
__global__ __launch_bounds__(256) void gates_kernel(
    const float* __restrict__ qb, const float* __restrict__ kb,
    const float* __restrict__ vb, const float* __restrict__ Wi,
    const float* __restrict__ bi, const float* __restrict__ Wf,
    const float* __restrict__ bf, float* __restrict__ ig, float* __restrict__ logf) {
    __shared__ float red[16][257];
    const int tok = blockIdx.x;
    const int tid = threadIdx.x;
    float aI[8], aF[8];
#pragma unroll
    for (int h = 0; h < 8; ++h) { aI[h] = 0.f; aF[h] = 0.f; }
    const size_t rb = (size_t)tok * INNER;
    for (int d = tid; d < INNER; d += 256) {
        float qv = qb[rb + d], kv = kb[rb + d], vv = vb[rb + d];
        float4 wq0 = *(const float4*)&Wi[(size_t)d * 8];
        float4 wq1 = *(const float4*)&Wi[(size_t)d * 8 + 4];
        float4 wk0 = *(const float4*)&Wi[(size_t)(INNER + d) * 8];
        float4 wk1 = *(const float4*)&Wi[(size_t)(INNER + d) * 8 + 4];
        float4 wv0 = *(const float4*)&Wi[(size_t)(2 * INNER + d) * 8];
        float4 wv1 = *(const float4*)&Wi[(size_t)(2 * INNER + d) * 8 + 4];
        aI[0] += qv * wq0.x + kv * wk0.x + vv * wv0.x;
        aI[1] += qv * wq0.y + kv * wk0.y + vv * wv0.y;
        aI[2] += qv * wq0.z + kv * wk0.z + vv * wv0.z;
        aI[3] += qv * wq0.w + kv * wk0.w + vv * wv0.w;
        aI[4] += qv * wq1.x + kv * wk1.x + vv * wv1.x;
        aI[5] += qv * wq1.y + kv * wk1.y + vv * wv1.y;
        aI[6] += qv * wq1.z + kv * wk1.z + vv * wv1.z;
        aI[7] += qv * wq1.w + kv * wk1.w + vv * wv1.w;
        float4 fq0 = *(const float4*)&Wf[(size_t)d * 8];
        float4 fq1 = *(const float4*)&Wf[(size_t)d * 8 + 4];
        float4 fk0 = *(const float4*)&Wf[(size_t)(INNER + d) * 8];
        float4 fk1 = *(const float4*)&Wf[(size_t)(INNER + d) * 8 + 4];
        float4 fv0 = *(const float4*)&Wf[(size_t)(2 * INNER + d) * 8];
        float4 fv1 = *(const float4*)&Wf[(size_t)(2 * INNER + d) * 8 + 4];
        aF[0] += qv * fq0.x + kv * fk0.x + vv * fv0.x;
        aF[1] += qv * fq0.y + kv * fk0.y + vv * fv0.y;
        aF[2] += qv * fq0.z + kv * fk0.z + vv * fv0.z;
        aF[3] += qv * fq0.w + kv * fk0.w + vv * fv0.w;
        aF[4] += qv * fq1.x + kv * fk1.x + vv * fv1.x;
        aF[5] += qv * fq1.y + kv * fk1.y + vv * fv1.y;
        aF[6] += qv * fq1.z + kv * fk1.z + vv * fv1.z;
        aF[7] += qv * fq1.w + kv * fk1.w + vv * fv1.w;
    }
#pragma unroll
    for (int h = 0; h < 8; ++h) { red[h][tid] = aI[h]; red[8 + h][tid] = aF[h]; }
    __syncthreads();
    for (int off = 128; off > 0; off >>= 1) {
        if (tid < off) {
#pragma unroll
            for (int h = 0; h < 16; ++h) red[h][tid] += red[h][tid + off];
        }
        __syncthreads();
    }
    if (tid < 8) {
        int h = tid;
        int b = tok / SEQ, s = tok % SEQ;
        size_t gidx = (size_t)(b * NHEADS + h) * SEQ + s;
        ig[gidx] = red[h][0] + bi[h];
        float fgv = red[8 + h][0] + bf[h];
        float lf = fminf(fgv, 0.f) - log1pf(expf(-fabsf(fgv)));
        logf[gidx] = lf;
    }
}

// ---------------------------------------------------------------------------
// per-(b,h) scans: cs = cumsum(logf) (in place), ej = ig - cs, pm = cummax(ej)
// ---------------------------------------------------------------------------
__global__ __launch_bounds__(256) void scan_gates(
    float* __restrict__ csb, const float* __restrict__ igb,
    float* __restrict__ ejg, float* __restrict__ pmg) {
    __shared__ float ts[256];
    const int tid = threadIdx.x;
    const size_t base = (size_t)blockIdx.x * SEQ;
    float v[8];
    float run = 0.f;
#pragma unroll
    for (int j = 0; j < 8; ++j) { run += csb[base + tid * 8 + j]; v[j] = run; }
    ts[tid] = run;
    __syncthreads();
    for (int off = 1; off < 256; off <<= 1) {
        float add = (tid >= off) ? ts[tid - off] : 0.f;
        __syncthreads();
        ts[tid] += add;
        __syncthreads();
    }
    float excl = (tid > 0) ? ts[tid - 1] : 0.f;
    float e[8];
#pragma unroll
    for (int j = 0; j < 8; ++j) {
        float c = v[j] + excl;
        csb[base + tid * 8 + j] = c;
        e[j] = igb[base + tid * 8 + j] - c;
        ejg[base + tid * 8 + j] = e[j];
    }
    __syncthreads();
    float m = -INFINITY;
    float pmv[8];
#pragma unroll
    for (int j = 0; j < 8; ++j) { m = fmaxf(m, e[j]); pmv[j] = m; }
    ts[tid] = m;
    __syncthreads();
    for (int off = 1; off < 256; off <<= 1) {
        float mm = (tid >= off) ? ts[tid - off] : -INFINITY;
        __syncthreads();
        ts[tid] = fmaxf(ts[tid], mm);
        __syncthreads();
    }
    float exm = (tid > 0) ? ts[tid - 1] : -INFINITY;
#pragma unroll
    for (int j = 0; j < 8; ++j) pmg[base + tid * 8 + j] = fmaxf(pmv[j], exm);
}

// ---------------------------------------------------------------------------
// q,k -> per-head padded bf16 hi/lo [bh][2][S][160]; k pre-scaled by 1/sqrt(DH)
// ---------------------------------------------------------------------------
#define DP 160

__global__ __launch_bounds__(256) void qk_convert(
    const float* __restrict__ qb, const float* __restrict__ kb,
    unsigned short* __restrict__ qh, unsigned short* __restrict__ kh) {
    int t = blockIdx.x * 256 + threadIdx.x;   // TOKENS*8*20 = 655360 exactly
    int seg = t % 20;
    int rest = t / 20;
    int h = rest & 7;
    int token = rest >> 3;
    int b = token >> 11, s = token & (SEQ - 1);
    int bh = b * 8 + h;
    int d0 = seg * 8;
    u16x8 qhi = {0,0,0,0,0,0,0,0}, qlo = qhi, khi = qhi, klo = qhi;
    if (d0 < DHEAD) {
        const float* qs = qb + (size_t)token * INNER + h * DHEAD + d0;
        const float* ks = kb + (size_t)token * INNER + h * DHEAD + d0;
        float4 a0 = *(const float4*)qs, a1 = *(const float4*)(qs + 4);
        float4 b0 = *(const float4*)ks, b1 = *(const float4*)(ks + 4);
        float qa[8] = {a0.x, a0.y, a0.z, a0.w, a1.x, a1.y, a1.z, a1.w};
        float ka[8] = {b0.x, b0.y, b0.z, b0.w, b1.x, b1.y, b1.z, b1.w};
#pragma unroll
        for (int j = 0; j < 8; ++j) {
            unsigned short hq = f2bf(qa[j]);
            qhi[j] = hq;
            qlo[j] = f2bf(qa[j] - bf2f(hq));
            float kv = ka[j] * (1.f / 12.f);
            unsigned short hk = f2bf(kv);
            khi[j] = hk;
            klo[j] = f2bf(kv - bf2f(hk));
        }
    }
    size_t hi_idx = ((size_t)(bh * 2) * SEQ + s) * DP + d0;
    size_t plane = (size_t)SEQ * DP;
    *(u16x8*)&qh[hi_idx] = qhi;
    *(u16x8*)&qh[hi_idx + plane] = qlo;
    *(u16x8*)&kh[hi_idx] = khi;
    *(u16x8*)&kh[hi_idx + plane] = klo;
}

// ---------------------------------------------------------------------------
// v -> transposed per-head bf16 hi/lo [bh][2][144][S]
// ---------------------------------------------------------------------------
__global__ __launch_bounds__(256) void v_transpose(
    const float* __restrict__ vb, unsigned short* __restrict__ vt) {
    __shared__ float ls[64][148];
    const int tid = threadIdx.x;
    const int sb = blockIdx.x;      // 0..31 (64-token blocks)
    const int bh = blockIdx.y;      // 0..15
    const int b = bh >> 3, h = bh & 7;
    for (int u = tid; u < 64 * 36; u += 256) {
        int s_ = u / 36, c4 = (u % 36) * 4;
        *(float4*)&ls[s_][c4] =
            *(const float4*)&vb[(size_t)(b * SEQ + sb * 64 + s_) * INNER + h * DHEAD + c4];
    }
    __syncthreads();
    for (int u = tid; u < 1152; u += 256) {
        int dd = u >> 3, sc = u & 7;
        u16x8 hi, lo;
#pragma unroll
        for (int i = 0; i < 8; ++i) {
            float a = ls[sc * 8 + i][dd];
            unsigned short hh = f2bf(a);
            hi[i] = hh;
            lo[i] = f2bf(a - bf2f(hh));
        }
        size_t dst = ((size_t)(bh * 2) * 144 + dd) * SEQ + sb * 64 + sc * 8;
        *(u16x8*)&vt[dst] = hi;
        *(u16x8*)&vt[dst + (size_t)144 * SEQ] = lo;
    }
}

// ---------------------------------------------------------------------------
// MFMA mLSTM cell.  Block = (bh, 64-row q tile); 4 waves x 16 q rows.
// Swapped QK^T (mfma(K,Q) -> q in lane&15), gate-only decay stats via
// precomputed cs/ej/pm (no online max machinery), bf16x3 split everywhere.
// ---------------------------------------------------------------------------
#define LKS 168   // K LDS row stride (u16): 21x16B -> conflict-free b128
#define LVS 40    // Vt LDS row stride (u16): 5x16B
#define PSTR 40   // P LDS row stride (u16)

__global__ __launch_bounds__(256) void mlstm_cell_mfma(
    const unsigned short* __restrict__ qh, const unsigned short* __restrict__ kh,
    const unsigned short* __restrict__ vt, const float* __restrict__ ejg,
    const float* __restrict__ pmg, const float* __restrict__ csg,
    float* __restrict__ hcell) {
    __shared__ unsigned short Ks[2][32][LKS];
    __shared__ unsigned short Vs[2][144][LVS];
    __shared__ unsigned short Pl[2][4][16][PSTR];
    __shared__ float ej_s[32];
    __shared__ float scl_s[4][16];
    __shared__ float nrm_s[4][16];

    const int n = blockIdx.x;
    const int bh = n & 15;
    const int ii = n >> 4;                            // 0..31
    // bijective triangular load-balance: 0,31,1,30,2,29,...
    const int qt = (ii & 1) ? (31 - (ii >> 1)) : (ii >> 1);
    const int b = bh >> 3, h = bh & 7;
    const int qb0 = qt * 64;
    const int tid = threadIdx.x;
    const int w = tid >> 6, lane = tid & 63;
    const int ql = lane & 15;
    const int ss = lane >> 4;
    const int q = qb0 + w * 16 + ql;
    const int gb = bh * SEQ;

    // Q B-fragments (5 ksteps x hi/lo), kept in registers for all kv tiles
    bf16x8 qf[2][5];
#pragma unroll
    for (int l = 0; l < 2; ++l) {
        size_t qbase = ((size_t)(bh * 2 + l) * SEQ + q) * DP;
#pragma unroll
        for (int ks = 0; ks < 5; ++ks)
            qf[l][ks] = *(const bf16x8*)&qh[qbase + ks * 32 + ss * 8];
    }

    f32x4 o[9];
#pragma unroll
    for (int j = 0; j < 9; ++j) o[j] = (f32x4){0.f, 0.f, 0.f, 0.f};
    float ssum = 0.f;
    float pm_run = -INFINITY;
    const int ntiles = 2 * (qt + 1);
    const int wlimit = (qb0 + w * 16 + 15) >> 5;

    for (int t = 0; t < ntiles; ++t) {
        const int kvb = t * 32;
        __syncthreads();
        // ---- stage K (1280 chunks), Vt (1152 chunks), ej ----
        for (int c = tid; c < 1280; c += 256) {
            int l = c / 640, rem = c % 640, row = rem / 20, seg = rem % 20;
            u16x8 vv = *(const u16x8*)&kh[((size_t)(bh * 2 + l) * SEQ + kvb + row) * DP + seg * 8];
            *(u16x8*)&Ks[l][row][seg * 8] = vv;
        }
        for (int c = tid; c < 1152; c += 256) {
            int l = c / 576, rem = c % 576, dd = rem / 4, seg = rem % 4;
            u16x8 vv = *(const u16x8*)&vt[((size_t)(bh * 2 + l) * 144 + dd) * SEQ + kvb + seg * 8];
            *(u16x8*)&Vs[l][dd][seg * 8] = vv;
        }
        if (tid < 32) ej_s[tid] = ejg[gb + kvb + tid];
        __syncthreads();

        const bool active = (t <= wlimit);
        // ---- phase 1: QK^T + decay weights + P (hi/lo) to LDS ----
        if (active) {
            const int eq = min(q, kvb + 31);
            const float pm_e = pmg[gb + eq];
            const float sc = __expf(pm_run - pm_e);   // t==0: exp(-inf)=0
            pm_run = pm_e;
            scl_s[w][ql] = sc;

            f32x4 s0 = {0.f, 0.f, 0.f, 0.f}, s1 = s0;
#pragma unroll
            for (int ks = 0; ks < 5; ++ks) {
                bf16x8 a0h = *(const bf16x8*)&Ks[0][ql][ks * 32 + ss * 8];
                bf16x8 a0l = *(const bf16x8*)&Ks[1][ql][ks * 32 + ss * 8];
                bf16x8 a1h = *(const bf16x8*)&Ks[0][16 + ql][ks * 32 + ss * 8];
                bf16x8 a1l = *(const bf16x8*)&Ks[1][16 + ql][ks * 32 + ss * 8];
                s0 = MF(a0h, qf[0][ks], s0);
                s0 = MF(a0h, qf[1][ks], s0);
                s0 = MF(a0l, qf[0][ks], s0);
                s1 = MF(a1h, qf[0][ks], s1);
                s1 = MF(a1h, qf[1][ks], s1);
                s1 = MF(a1l, qf[0][ks], s1);
            }
            float lsum = 0.f;
            float pq[2][4];
#pragma unroll
            for (int f = 0; f < 2; ++f) {
#pragma unroll
                for (int r = 0; r < 4; ++r) {
                    int kv = kvb + f * 16 + 4 * ss + r;
                    float sv = f ? s1[r] : s0[r];
                    float wgt = (kv <= q) ? __expf(ej_s[f * 16 + 4 * ss + r] - pm_e) : 0.f;
                    float p = sv * wgt;
                    pq[f][r] = p;
                    lsum += p;
                }
            }
            ssum = ssum * sc + lsum;
#pragma unroll
            for (int f = 0; f < 2; ++f) {
                unsigned short h0 = f2bf(pq[f][0]), h1 = f2bf(pq[f][1]);
                unsigned short h2 = f2bf(pq[f][2]), h3 = f2bf(pq[f][3]);
                unsigned hi01 = (unsigned)h0 | ((unsigned)h1 << 16);
                unsigned hi23 = (unsigned)h2 | ((unsigned)h3 << 16);
                unsigned short l0 = f2bf(pq[f][0] - bf2f(h0)), l1 = f2bf(pq[f][1] - bf2f(h1));
                unsigned short l2 = f2bf(pq[f][2] - bf2f(h2)), l3 = f2bf(pq[f][3] - bf2f(h3));
                unsigned lo01 = (unsigned)l0 | ((unsigned)l1 << 16);
                unsigned lo23 = (unsigned)l2 | ((unsigned)l3 << 16);
                uint2 hv = {hi01, hi23}, lv = {lo01, lo23};
                *(uint2*)&Pl[0][w][ql][4 * ss + 16 * f] = hv;
                *(uint2*)&Pl[1][w][ql][4 * ss + 16 * f] = lv;
            }
        }
        __syncthreads();
        // ---- phase 2: PV accumulate with rescale ----
        if (active) {
            bf16x8 ph = *(const bf16x8*)&Pl[0][w][ql][ss * 8];
            bf16x8 pl = *(const bf16x8*)&Pl[1][w][ql][ss * 8];
            float scr[4];
#pragma unroll
            for (int r = 0; r < 4; ++r) scr[r] = scl_s[w][4 * ss + r];
#pragma unroll
            for (int j = 0; j < 9; ++j) {
                f32x4 tacc = o[j];
                tacc[0] *= scr[0]; tacc[1] *= scr[1];
                tacc[2] *= scr[2]; tacc[3] *= scr[3];
                bf16x8 vh = *(const bf16x8*)&Vs[0][16 * j + ql][ss * 8];
                bf16x8 vl = *(const bf16x8*)&Vs[1][16 * j + ql][ss * 8];
                tacc = MF(ph, vh, tacc);
                tacc = MF(pl, vh, tacc);
                tacc = MF(ph, vl, tacc);
                o[j] = tacc;
            }
        }
    }

    // ---- epilogue: normalizer + store ----
    ssum += __shfl_xor(ssum, 16);
    ssum += __shfl_xor(ssum, 32);
    float m = csg[gb + q] + pm_run;
    float nrm = fmaxf(fabsf(ssum), __expf(-m)) + 1e-6f;
    nrm_s[w][ql] = 1.f / nrm;
    __syncthreads();
    float invr[4];
#pragma unroll
    for (int r = 0; r < 4; ++r) invr[r] = nrm_s[w][4 * ss + r];
    const size_t hb = ((size_t)(b * SEQ + qb0 + w * 16)) * INNER + h * DHEAD;
#pragma unroll
    for (int j = 0; j < 9; ++j)
#pragma unroll
        for (int r = 0; r < 4; ++r)
            hcell[hb + (size_t)(4 * ss + r) * INNER + 16 * j + ql] = o[j][r] * invr[r];
}

// ---------------------------------------------------------------------------
// per-head layernorm * norm_w + skip*x_conv, then * silu(z)
// ---------------------------------------------------------------------------
__global__ __launch_bounds__(256) void ln_gate(
    const float* __restrict__ hcell, const float* __restrict__ xconv,
    const float* __restrict__ xz, const float* __restrict__ norm_w,
    const float* __restrict__ skip, float* __restrict__ g) {
    const int unit = blockIdx.x * 4 + (threadIdx.x >> 6);
    const int lane = threadIdx.x & 63;
    const int token = unit >> 3;
    const int h = unit & 7;
    const size_t base = (size_t)token * INNER + h * DHEAD;

    float x0 = hcell[base + lane];
    float x1 = hcell[base + 64 + lane];
    float x2 = (lane < 16) ? hcell[base + 128 + lane] : 0.f;
    float s = x0 + x1 + x2;
#pragma unroll
    for (int off = 32; off > 0; off >>= 1) s += __shfl_down(s, off);
    s = __shfl(s, 0);
    float mean = s * (1.f / 144.f);
    float d0 = x0 - mean, d1 = x1 - mean, d2 = (lane < 16) ? x2 - mean : 0.f;
    float vsum = d0 * d0 + d1 * d1 + d2 * d2;
#pragma unroll
    for (int off = 32; off > 0; off >>= 1) vsum += __shfl_down(vsum, off);
    vsum = __shfl(vsum, 0);
    float rstd = rsqrtf(vsum * (1.f / 144.f) + 1e-5f);
    float sk = skip[0];
    const size_t zbase = (size_t)token * (2 * INNER) + INNER + h * DHEAD;

    {
        float hn = d0 * rstd * norm_w[h * DHEAD + lane];
        g[base + lane] = (hn + sk * xconv[base + lane]) * silu_f(xz[zbase + lane]);
    }
    {
        float hn = d1 * rstd * norm_w[h * DHEAD + 64 + lane];
        g[base + 64 + lane] = (hn + sk * xconv[base + 64 + lane]) * silu_f(xz[zbase + 64 + lane]);
    }
    if (lane < 16) {
        float hn = d2 * rstd * norm_w[h * DHEAD + 128 + lane];
        g[base + 128 + lane] = (hn + sk * xconv[base + 128 + lane]) * silu_f(xz[zbase + 128 + lane]);
    }
}

// ---------------------------------------------------------------------------
extern "C" void kernel_launch(void* const* d_in, const int* in_sizes, int n_in,
                              void* d_out, int out_size, void* d_ws, size_t ws_size,
                              hipStream_t stream) {
    const float* x      = (const float*)d_in[0];
    const float* W_up   = (const float*)d_in[1];
    const float* conv_w = (const float*)d_in[2];
    const float* conv_b = (const float*)d_in[3];
    const float* Wq     = (const float*)d_in[4];
    const float* Wk     = (const float*)d_in[5];
    const float* Wv     = (const float*)d_in[6];
    const float* Wi     = (const float*)d_in[7];
    const float* bi     = (const float*)d_in[8];
    const float* Wf     = (const float*)d_in[9];
    const float* bf     = (const float*)d_in[10];
    const float* norm_w = (const float*)d_in[11];
    const float* skip   = (const float*)d_in[12];
    const float* W_down = (const float*)d_in[13];
    float* out = (float*)d_out;

    // ---- workspace layout (units: floats). bf16 hi/lo buffers need
    // (elements * 2 levels) u16 = (elements) floats. Aliased regions are
    // annotated with liveness; all launches are stream-ordered.
    float* f = (float*)d_ws;
    float* xz    = f; f += 9437184;          // TOKENS*2*INNER
    float* xconv = f; f += 4718592;          // TOKENS*INNER
    float* qb    = f; f += 4718592;
    float* kbuf  = f; f += 4718592;
    float* vb    = f; f += 4718592;
    float* hcell = f; f += 4718592;
    float* igb   = f; f += 32768;
    float* csb   = f; f += 32768;
    float* ejg   = f; f += 32768;
    float* pmg   = f; f += 32768;
    // region A (7864320 fl): xh [steps 2] + ch [steps 3-4]; then kht [6-7]; gh [8]
    float* regA = f; f += 7864320;
    unsigned short* xh  = (unsigned short*)regA;              // 4096*768*2 u16 = 3145728 fl
    unsigned short* ch  = (unsigned short*)(regA + 3145728);  // 4096*1152*2 u16 = 4718592 fl
    unsigned short* kht = (unsigned short*)regA;              // 16*2*2048*160 u16 = 5242880 fl
    unsigned short* gh  = (unsigned short*)(regA + 3145728);  // 4718592 fl
    // region B (4718592 fl): mh [3-4]; then vtt [6-7]
    float* regB = f; f += 4718592;
    unsigned short* mh  = (unsigned short*)regB;
    unsigned short* vtt = (unsigned short*)regB;              // 16*2*144*2048 u16
    // region C (5750784 fl): wup(1769472)+wqt(1327104)+wkt(1327104)+wvt(1327104)
    // [steps 1-4]; then qht (5242880 fl) [6-7]
    float* regC = f; f += 5750784;
    unsigned short* wup = (unsigned short*)regC;
    unsigned short* wqt = (unsigned short*)(regC + 1769472);
    unsigned short* wkt = (unsigned short*)(regC + 3096576);
    unsigned short* wvt = (unsigned short*)(regC + 4423680);
    unsigned short* qht = (unsigned short*)regC;
    float* wdtf = f; f += 884736;            // 1152*768*2 u16 — live to step 8
    unsigned short* wdt = (unsigned short*)wdtf;

    dim3 blk(256);

    // 1. weight conversions
    convert_wgt<<<dim3(18, 24), blk, 0, stream>>>(W_up, 2304, 768, wup);
    convert_wgt<<<dim3(9, 36), blk, 0, stream>>>(Wq, 1152, 1152, wqt);
    convert_wgt<<<dim3(9, 36), blk, 0, stream>>>(Wk, 1152, 1152, wkt);
    convert_wgt<<<dim3(9, 36), blk, 0, stream>>>(Wv, 1152, 1152, wvt);
    convert_wgt<<<dim3(6, 36), blk, 0, stream>>>(W_down, 768, 1152, wdt);

    // 2. up-proj
    convert_act<<<1536, blk, 0, stream>>>(x, HDIM, HDIM, xh);
    gemm_bf16x3<<<dim3(18, 32), blk, 0, stream>>>(xh, wup, xz, 2304, 24);

    // 3. conv + silu; x_mlstm tiles
    conv_silu_cvt<<<2304, blk, 0, stream>>>(xz, conv_w, conv_b, xconv, ch);
    convert_act<<<2304, blk, 0, stream>>>(xz, 2 * INNER, INNER, mh);

    // 4. q, k, v projections
    gemm_bf16x3<<<dim3(9, 32), blk, 0, stream>>>(ch, wqt, qb, INNER, 36);
    gemm_bf16x3<<<dim3(9, 32), blk, 0, stream>>>(ch, wkt, kbuf, INNER, 36);
    gemm_bf16x3<<<dim3(9, 32), blk, 0, stream>>>(mh, wvt, vb, INNER, 36);

    // 5. gates + scans
    gates_kernel<<<TOKENS, blk, 0, stream>>>(qb, kbuf, vb, Wi, bi, Wf, bf, igb, csb);
    scan_gates<<<BATCH * NHEADS, blk, 0, stream>>>(csb, igb, ejg, pmg);

    // 6. cell operand conversion (overwrites dead regions A/B/C)
    qk_convert<<<2560, blk, 0, stream>>>(qb, kbuf, qht, kht);
    v_transpose<<<dim3(32, 16), blk, 0, stream>>>(vb, vtt);
    // 7. MFMA cell
    mlstm_cell_mfma<<<512, blk, 0, stream>>>(qht, kht, vtt, ejg, pmg, csb, hcell);

    // 8. LN + skip + z-gate (into qb), convert (into ch-slot), down-proj
    ln_gate<<<TOKENS * NHEADS / 4, blk, 0, stream>>>(hcell, xconv, xz, norm_w, skip, qb);
    convert_act<<<2304, blk, 0, stream>>>(qb, INNER, INNER, gh);
    gemm_bf16x3<<<dim3(6, 32), blk, 0, stream>>>(gh, wdt, out, HDIM, 36);
}